// Round 7
// baseline (3924.829 us; speedup 1.0000x reference)
//
#include <hip/hip_runtime.h>
#include <hip/hip_bf16.h>

// Problem constants (BinaryClassifyModel: L=6, B=8, S=2048, H=768, V=32000)
#define Bn 8
#define Sn 2048
#define Hn 768
#define FFn 3072
#define Ln 6
#define BSn (Bn * Sn)       // 16384 tokens
#define CQ 512              // query chunk for attention scores buffer
#define LN_EPS 1e-5f

typedef __hip_bfloat16 bf16;
typedef __bf16 bf16x8 __attribute__((ext_vector_type(8)));
typedef float f32x4 __attribute__((ext_vector_type(4)));

__device__ __forceinline__ float b2f(bf16 v) { return __bfloat162float(v); }
__device__ __forceinline__ void stc(float* p, float v) { *p = v; }
__device__ __forceinline__ void stc(bf16* p, float v) { *p = __float2bfloat16(v); }

union Pk8 { float4 v; bf16 h[8]; };   // 8 consecutive bf16 = one 16B load

// async global->LDS, 16B per lane; LDS dest = wave-uniform base + lane*16
__device__ __forceinline__ void gld16(const bf16* g, short* l) {
  __builtin_amdgcn_global_load_lds(
      (const __attribute__((address_space(1))) unsigned int*)g,
      (__attribute__((address_space(3))) unsigned int*)l, 16, 0, 0);
}

#define BAR() __builtin_amdgcn_s_barrier()
#define VMC(n) asm volatile("s_waitcnt vmcnt(" #n ")" ::: "memory")

// exact-GELU via A&S 7.1.26 erf polynomial on v/sqrt(2), |eps| <= 1.5e-7
__device__ __forceinline__ float gelu_exact(float v) {
  float a = fabsf(v) * 0.70710678118654752f;   // |v| / sqrt(2)
  float t = 1.0f / (1.0f + 0.3275911f * a);
  float poly = t * (0.254829592f +
               t * (-0.284496736f +
               t * (1.421413741f +
               t * (-1.453152027f + t * 1.061405429f))));
  float er = 1.0f - poly * __expf(-a * a);
  er = v < 0.f ? -er : er;
  return 0.5f * v * (1.0f + er);
}

// ---------------------------------------------------------------------------
// Embedding
// ---------------------------------------------------------------------------
__global__ void __launch_bounds__(256) embed_kernel(
    const int* __restrict__ ids, const float* __restrict__ tok,
    const float* __restrict__ pos, float* __restrict__ x) {
  long t = blockIdx.x;
  int s = (int)(t & (Sn - 1));
  long id = ids[t];
  const float* tr = tok + id * Hn;
  const float* pr = pos + (long)s * Hn;
  float* xr = x + t * Hn;
  for (int d = threadIdx.x; d < Hn; d += 256)
    xr[d] = tr[d] + pr[d];
}

// ---------------------------------------------------------------------------
// All-weights transpose + cast for one layer, single launch (6912 blocks).
// ---------------------------------------------------------------------------
__global__ void __launch_bounds__(256) transpose_all_kernel(
    const float* __restrict__ Wq_l, const float* __restrict__ Wk_l,
    const float* __restrict__ Wv_l, const float* __restrict__ Wo_l,
    const float* __restrict__ W1_l, const float* __restrict__ W2_l,
    bf16* __restrict__ wt) {
  int id = blockIdx.x;
  const float* W;
  bf16* Wt;
  int K, N, tile, tilesX;
  if (id < 2304) {
    int w = id / 576;
    tile = id - w * 576;
    W = (w == 0) ? Wq_l : (w == 1) ? Wk_l : (w == 2) ? Wv_l : Wo_l;
    Wt = wt + (size_t)w * Hn * Hn;
    K = Hn; N = Hn; tilesX = Hn / 32;
  } else if (id < 4608) {
    tile = id - 2304;
    W = W1_l;
    Wt = wt + 4 * (size_t)Hn * Hn;
    K = Hn; N = FFn; tilesX = FFn / 32;
  } else {
    tile = id - 4608;
    W = W2_l;
    Wt = wt + 4 * (size_t)Hn * Hn + (size_t)Hn * FFn;
    K = FFn; N = Hn; tilesX = Hn / 32;
  }
  int n0 = (tile % tilesX) * 32, k0 = (tile / tilesX) * 32;

  __shared__ float t[32][33];
  int tx = threadIdx.x & 31, ty = threadIdx.x >> 5;
#pragma unroll
  for (int i = 0; i < 32; i += 8)
    t[ty + i][tx] = W[(long)(k0 + ty + i) * N + n0 + tx];
  __syncthreads();
#pragma unroll
  for (int i = 0; i < 32; i += 8)
    stc(Wt + (long)(n0 + ty + i) * K + k0 + tx, t[tx][ty + i]);
}

// ---------------------------------------------------------------------------
// LayerNorm
// ---------------------------------------------------------------------------
__global__ void __launch_bounds__(256) ln_kernel(
    const float* __restrict__ x, const float* __restrict__ g,
    const float* __restrict__ b, bf16* __restrict__ out) {
  long token = blockIdx.x;
  const float* xr = x + token * Hn;
  bf16* orow = out + token * Hn;
  int tid = threadIdx.x;

  float vals[3];
  float s1 = 0.f;
#pragma unroll
  for (int i = 0; i < 3; i++) {
    vals[i] = xr[tid + 256 * i];
    s1 += vals[i];
  }
  __shared__ float sb[4];
  __shared__ float stat[2];
#pragma unroll
  for (int off = 32; off > 0; off >>= 1) s1 += __shfl_down(s1, off, 64);
  if ((tid & 63) == 0) sb[tid >> 6] = s1;
  __syncthreads();
  if (tid == 0) stat[0] = (sb[0] + sb[1] + sb[2] + sb[3]) * (1.0f / Hn);
  __syncthreads();
  float mean = stat[0];

  float s2 = 0.f;
#pragma unroll
  for (int i = 0; i < 3; i++) {
    float d = vals[i] - mean;
    s2 += d * d;
  }
#pragma unroll
  for (int off = 32; off > 0; off >>= 1) s2 += __shfl_down(s2, off, 64);
  if ((tid & 63) == 0) sb[tid >> 6] = s2;
  __syncthreads();
  if (tid == 0)
    stat[1] = rsqrtf((sb[0] + sb[1] + sb[2] + sb[3]) * (1.0f / Hn) + LN_EPS);
  __syncthreads();
  float inv = stat[1];

#pragma unroll
  for (int i = 0; i < 3; i++) {
    int d = tid + 256 * i;
    stc(orow + d, (vals[i] - mean) * inv * g[d] + b[d]);
  }
}

// ---------------------------------------------------------------------------
// 128x128 MFMA GEMM — 4 waves, BK=32, 32 KiB dbuf LDS, 4 blocks/CU.
//   Theory: prior 256² config was 1 block/CU (single barrier domain) and every
//   pipe sat at ~30%; this trades tile size for 4 independent blocks/CU
//   (16 waves) so other blocks cover each block's vmcnt/barrier stalls.
//   LDS (bytes): buf b at b*16384: A[128][32] @ +0, B[128][32] @ +8192.
//   64B rows; write-side pre-swizzle kswz = ((lane&3)^(row&3))*8 elems,
//   read-side byte ^= (l16&3)<<4 (same involution; residual 4-way conflict).
//   Per tile: stage tile T+1 (issue-early), 8 ds_read_b128 + 16 MFMA,
//   vmcnt(0)+barrier.  __launch_bounds__(256,4) caps regs for 4 waves/SIMD.
//   EPI: 1 = bias+res (f32 out), 2 = gelu(bias) (bf16), 4 = fused QKV.
//   Assumes M%128==0, N%128==0, K%64==0 (NT even >=2), grid%8==0.
// ---------------------------------------------------------------------------
template <int EPI, typename CT>
__global__ void __launch_bounds__(256, 4) gemm128_kernel(
    const bf16* __restrict__ A, const bf16* __restrict__ Bt,
    const float* __restrict__ bias, const float* __restrict__ res,
    CT* __restrict__ C, int M, int N, int K,
    const float* __restrict__ bias2, const float* __restrict__ bias3) {
  __shared__ short lds[16384];         // 32 KiB
  int tid = threadIdx.x;
  int wave = tid >> 6, lane = tid & 63;
  int wm = wave >> 1, wn = wave & 1;   // 2 x 2 wave grid, 64x64 per wave
  int quad = lane >> 4, l16 = lane & 15;
  int swz = (l16 & 3) << 4;            // read-side XOR (bytes within 64B row)
  int g = lane >> 2;                   // staging: row within 16-row chunk
  int kswz = ((lane & 3) ^ (g & 3)) * 8;  // staging pre-swizzled k-off (elems)

  // bijective XCD-chunked swizzle (grid%8==0 for all our launches)
  int nwg = gridDim.x, orig = blockIdx.x;
  int q8 = nwg >> 3, r8 = nwg & 7;
  int xcd = orig & 7, loc = orig >> 3;
  int wg = (xcd < r8 ? xcd * (q8 + 1) : r8 * (q8 + 1) + (xcd - r8) * q8) + loc;
  int gx = N >> 7;
  long colBase = (long)(wg % gx) * 128;
  long rowBase = (long)(wg / gx) * 128;

  // per-lane global stage bases (bumped +64 elements per tile pair)
  const bf16* aSrc = A + rowBase * K + (long)g * K + kswz;
  const bf16* bSrc = Bt + colBase * K + (long)g * K + kswz;

  // wave-uniform stage row groups (2 x 16-row chunks per wave, A and B)
  int r0A0 = wave * 32, r0A1 = wave * 32 + 16;
  long sA0 = (long)r0A0 * K, sA1 = (long)r0A1 * K;   // B uses same rows

  // hoisted per-lane LDS read bases (buffer select is an immediate)
  char* lb = (char*)lds;
  const char* aRd = lb + (wm * 64 + l16) * 64 + ((quad * 16) ^ swz);
  const char* bRd = lb + 8192 + (wn * 64 + l16) * 64 + ((quad * 16) ^ swz);

  f32x4 acc[4][4] = {};
  bf16x8 af[4], bfr[4];

#define STAGE(BUF, KOFF)                                                    \
  {                                                                         \
    gld16(aSrc + sA0 + (KOFF), (short*)(lb + (BUF) * 16384 + r0A0 * 64));   \
    gld16(aSrc + sA1 + (KOFF), (short*)(lb + (BUF) * 16384 + r0A1 * 64));   \
    gld16(bSrc + sA0 + (KOFF),                                              \
          (short*)(lb + (BUF) * 16384 + 8192 + r0A0 * 64));                 \
    gld16(bSrc + sA1 + (KOFF),                                              \
          (short*)(lb + (BUF) * 16384 + 8192 + r0A1 * 64));                 \
  }
#define COMPUTE(BUF)                                                        \
  {                                                                         \
    _Pragma("unroll") for (int i_ = 0; i_ < 4; i_++)                        \
        af[i_] = *(const bf16x8*)(aRd + (BUF) * 16384 + i_ * 1024);         \
    _Pragma("unroll") for (int j_ = 0; j_ < 4; j_++)                        \
        bfr[j_] = *(const bf16x8*)(bRd + (BUF) * 16384 + j_ * 1024);        \
    __builtin_amdgcn_s_setprio(1);                                          \
    _Pragma("unroll") for (int i_ = 0; i_ < 4; i_++)                        \
        _Pragma("unroll") for (int j_ = 0; j_ < 4; j_++)                    \
            acc[i_][j_] = __builtin_amdgcn_mfma_f32_16x16x32_bf16(          \
                af[i_], bfr[j_], acc[i_][j_], 0, 0, 0);                     \
    __builtin_amdgcn_s_setprio(0);                                          \
  }

  int NT = K >> 5;   // even, >= 2
  STAGE(0, 0);       // tile 0 -> buf0
  VMC(0); BAR();

  for (int T = 0; T < NT; T += 2) {
    STAGE(1, 32);                    // tile T+1 -> buf1 (issue-early)
    COMPUTE(0);                      // tile T from buf0
    VMC(0); BAR();
    if (T + 2 < NT) STAGE(0, 64);    // tile T+2 -> buf0
    COMPUTE(1);                      // tile T+1 from buf1
    VMC(0); BAR();
    aSrc += 64; bSrc += 64;
  }

  // epilogue: D col=lane&15, row=quad*4+reg
#pragma unroll
  for (int mi = 0; mi < 4; mi++) {
#pragma unroll
    for (int nj = 0; nj < 4; nj++) {
      int col = (int)colBase + wn * 64 + nj * 16 + l16;
      long row0 = rowBase + wm * 64 + mi * 16 + quad * 4;
      if (EPI == 4) {
        if (col < 1536) {
          float bv = col < 768 ? bias[col] : bias2[col - 768];
          bf16* dst = (bf16*)C + (col < 768 ? 0 : (size_t)BSn * Hn - Hn);
#pragma unroll
          for (int r = 0; r < 4; r++)
            stc(dst + (row0 + r) * Hn + col, acc[mi][nj][r] + bv);
        } else {
          int vcol = col - 1536;
          float bv = bias3[vcol];
          union { uint2 w; bf16 h[4]; } pk;
          long bb = row0 >> 11;          // token / Sn
          long s = row0 & (Sn - 1);      // token % Sn (block spans one batch)
#pragma unroll
          for (int r = 0; r < 4; r++)
            pk.h[r] = __float2bfloat16(acc[mi][nj][r] + bv);
          bf16* vT = (bf16*)C + 2 * (size_t)BSn * Hn;
          *reinterpret_cast<uint2*>(vT + (bb * Hn + vcol) * Sn + s) = pk.w;
        }
      } else {
        float bv = bias[col];
#pragma unroll
        for (int r = 0; r < 4; r++) {
          long row = row0 + r;
          float v = acc[mi][nj][r] + bv;
          if (EPI == 1) v += res[row * N + col];
          if (EPI == 2) v = gelu_exact(v);
          stc(C + row * N + col, v);
        }
      }
    }
  }
#undef STAGE
#undef COMPUTE
}

// ---------------------------------------------------------------------------
// QK^T via MFMA (128x128, causal early-out)
// ---------------------------------------------------------------------------
__global__ void __launch_bounds__(256) qk_mfma_kernel(
    const bf16* __restrict__ q, const bf16* __restrict__ k,
    bf16* __restrict__ sc, int q0) {
  int kBase = blockIdx.x * 128;
  int qBase = q0 + blockIdx.y * 128;
  if (kBase > qBase + 127) return;
  int b = blockIdx.z;
  const bf16* Ag = q + ((long)b * Sn + qBase) * Hn;
  const bf16* Bg = k + ((long)b * Sn + kBase) * Hn;

  __shared__ short As[128 * 32];
  __shared__ short Bs[128 * 32];
  int tid = threadIdx.x;
  int wave = tid >> 6, lane = tid & 63;
  int waveM = wave >> 1, waveN = wave & 1;
  int quad = lane >> 4, l16 = lane & 15;
  int srow = lane >> 2;
  int schunk = (lane & 3) * 8;

  f32x4 acc[4][4] = {};

  for (int kt = 0; kt < Hn; kt += 32) {
#pragma unroll
    for (int c = 0; c < 2; c++) {
      int r0 = wave * 32 + c * 16;
      gld16(Ag + (long)(r0 + srow) * Hn + kt + schunk, &As[r0 * 32]);
      gld16(Bg + (long)(r0 + srow) * Hn + kt + schunk, &Bs[r0 * 32]);
    }
    __syncthreads();

    bf16x8 af[4], bfrg[4];
#pragma unroll
    for (int t = 0; t < 4; t++)
      af[t] = *(const bf16x8*)&As[(waveM * 64 + t * 16 + l16) * 32 + quad * 8];
#pragma unroll
    for (int u = 0; u < 4; u++)
      bfrg[u] = *(const bf16x8*)&Bs[(waveN * 64 + u * 16 + l16) * 32 + quad * 8];
#pragma unroll
    for (int t = 0; t < 4; t++)
#pragma unroll
      for (int u = 0; u < 4; u++)
        acc[t][u] = __builtin_amdgcn_mfma_f32_16x16x32_bf16(af[t], bfrg[u],
                                                            acc[t][u], 0, 0, 0);
    __syncthreads();
  }

  const float scale = 0.03608439182435161f;  // 1/sqrt(768)
#pragma unroll
  for (int t = 0; t < 4; t++)
#pragma unroll
    for (int u = 0; u < 4; u++) {
      int col = kBase + waveN * 64 + u * 16 + l16;
#pragma unroll
      for (int r = 0; r < 4; r++) {
        long qRel = (long)(qBase - q0) + waveM * 64 + t * 16 + quad * 4 + r;
        stc(sc + ((long)b * CQ + qRel) * Sn + col, acc[t][u][r] * scale);
      }
    }
}

// ---------------------------------------------------------------------------
// P @ V via MFMA (128x128; vT operand; causal K-limit)
// ---------------------------------------------------------------------------
__global__ void __launch_bounds__(256) pv_mfma_kernel(
    const bf16* __restrict__ p, const bf16* __restrict__ vT,
    bf16* __restrict__ o, int q0) {
  int colBase = blockIdx.x * 128;
  int qBase = q0 + blockIdx.y * 128;
  int b = blockIdx.z;
  int klimit = qBase + 128;
  const bf16* Ag = p + ((long)b * CQ + (qBase - q0)) * Sn;
  const bf16* Bg = vT + ((long)b * Hn + colBase) * Sn;

  __shared__ short As[128 * 32];
  __shared__ short Bs[128 * 32];
  int tid = threadIdx.x;
  int wave = tid >> 6, lane = tid & 63;
  int waveM = wave >> 1, waveN = wave & 1;
  int quad = lane >> 4, l16 = lane & 15;
  int srow = lane >> 2;
  int schunk = (lane & 3) * 8;

  f32x4 acc[4][4] = {};

  for (int kt = 0; kt < klimit; kt += 32) {
#pragma unroll
    for (int c = 0; c < 2; c++) {
      int r0 = wave * 32 + c * 16;
      gld16(Ag + (long)(r0 + srow) * Sn + kt + schunk, &As[r0 * 32]);
      gld16(Bg + (long)(r0 + srow) * Sn + kt + schunk, &Bs[r0 * 32]);
    }
    __syncthreads();

    bf16x8 af[4], bfrg[4];
#pragma unroll
    for (int t = 0; t < 4; t++)
      af[t] = *(const bf16x8*)&As[(waveM * 64 + t * 16 + l16) * 32 + quad * 8];
#pragma unroll
    for (int u = 0; u < 4; u++)
      bfrg[u] = *(const bf16x8*)&Bs[(waveN * 64 + u * 16 + l16) * 32 + quad * 8];
#pragma unroll
    for (int t = 0; t < 4; t++)
#pragma unroll
      for (int u = 0; u < 4; u++)
        acc[t][u] = __builtin_amdgcn_mfma_f32_16x16x32_bf16(af[t], bfrg[u],
                                                            acc[t][u], 0, 0, 0);
    __syncthreads();
  }

#pragma unroll
  for (int t = 0; t < 4; t++)
#pragma unroll
    for (int u = 0; u < 4; u++) {
      int col = colBase + waveN * 64 + u * 16 + l16;
#pragma unroll
      for (int r = 0; r < 4; r++) {
        long qAbs = (long)qBase + waveM * 64 + t * 16 + quad * 4 + r;
        stc(o + ((long)b * Sn + qAbs) * Hn + col, acc[t][u][r]);
      }
    }
}

// ---------------------------------------------------------------------------
// Softmax (vectorized bf16x8); zero-fills to 128-aligned limit for PV.
// ---------------------------------------------------------------------------
__global__ void __launch_bounds__(256) softmax_kernel(
    bf16* __restrict__ sc, const int* __restrict__ mask, int q0) {
  int qRel = blockIdx.x;
  int b = blockIdx.y;
  int qg = q0 + qRel;
  bf16* row = sc + ((long)b * CQ + qRel) * Sn;
  const int* mrow = mask + b * Sn;
  int tid = threadIdx.x;
  int n = qg + 1;
  int limit = (qg & ~127) + 128;
  int k0 = tid * 8;

  Pk8 pk;
  pk.v = *reinterpret_cast<const float4*>(row + k0);
  int4 m0 = *reinterpret_cast<const int4*>(mrow + k0);
  int4 m1 = *reinterpret_cast<const int4*>(mrow + k0 + 4);
  int mm[8] = {m0.x, m0.y, m0.z, m0.w, m1.x, m1.y, m1.z, m1.w};

  float sv[8];
  float lmax = -1e30f;
#pragma unroll
  for (int j = 0; j < 8; j++) {
    int kk = k0 + j;
    float s = (kk < n && mm[j] != 0) ? b2f(pk.h[j]) : -1e30f;
    sv[j] = s;
    lmax = fmaxf(lmax, s);
  }
  __shared__ float sb[4];
  __shared__ float stat;
#pragma unroll
  for (int off = 32; off > 0; off >>= 1)
    lmax = fmaxf(lmax, __shfl_down(lmax, off, 64));
  if ((tid & 63) == 0) sb[tid >> 6] = lmax;
  __syncthreads();
  if (tid == 0) stat = fmaxf(fmaxf(sb[0], sb[1]), fmaxf(sb[2], sb[3]));
  __syncthreads();
  float gmax = stat;

  float ev[8];
  float lsum = 0.f;
#pragma unroll
  for (int j = 0; j < 8; j++) {
    float e = (sv[j] > -1e29f) ? __expf(sv[j] - gmax) : 0.f;
    ev[j] = e;
    lsum += e;
  }
#pragma unroll
  for (int off = 32; off > 0; off >>= 1) lsum += __shfl_down(lsum, off, 64);
  if ((tid & 63) == 0) sb[tid >> 6] = lsum;
  __syncthreads();
  if (tid == 0) stat = sb[0] + sb[1] + sb[2] + sb[3];
  __syncthreads();
  float inv = 1.0f / stat;

  if (k0 < limit) {
    Pk8 o;
#pragma unroll
    for (int j = 0; j < 8; j++)
      o.h[j] = __float2bfloat16((k0 + j < n) ? ev[j] * inv : 0.f);
    *reinterpret_cast<float4*>(row + k0) = o.v;
  }
}

// ---------------------------------------------------------------------------
// Classifier head
// ---------------------------------------------------------------------------
__global__ void __launch_bounds__(256) cls_kernel(
    const bf16* __restrict__ h, const int* __restrict__ mask,
    const float* __restrict__ clsW, const float* __restrict__ clsb,
    float* __restrict__ out) {
  int b = blockIdx.x;
  int tid = threadIdx.x;
  __shared__ float sb[4];
  __shared__ int ib[4];
  __shared__ int lastsh;

  int ls = 0;
  for (int s = tid; s < Sn; s += 256) ls += mask[b * Sn + s];
#pragma unroll
  for (int off = 32; off > 0; off >>= 1) ls += __shfl_down(ls, off, 64);
  if ((tid & 63) == 0) ib[tid >> 6] = ls;
  __syncthreads();
  if (tid == 0) lastsh = ib[0] + ib[1] + ib[2] + ib[3] - 1;
  __syncthreads();
  int last = lastsh;

  const bf16* row = h + ((long)b * Sn + last) * Hn;
  float acc = 0.f;
  for (int d = tid; d < Hn; d += 256) acc += b2f(row[d]) * clsW[d];
#pragma unroll
  for (int off = 32; off > 0; off >>= 1) acc += __shfl_down(acc, off, 64);
  if ((tid & 63) == 0) sb[tid >> 6] = acc;
  __syncthreads();
  if (tid == 0) out[b] = sb[0] + sb[1] + sb[2] + sb[3] + clsb[0];
}

// ---------------------------------------------------------------------------
// Orchestration
// ---------------------------------------------------------------------------
extern "C" void kernel_launch(void* const* d_in, const int* in_sizes, int n_in,
                              void* d_out, int out_size, void* d_ws,
                              size_t ws_size, hipStream_t stream) {
  const int* ids     = (const int*)d_in[0];
  const int* mask    = (const int*)d_in[1];
  const float* tok   = (const float*)d_in[2];
  const float* pos   = (const float*)d_in[3];
  const float* Wq    = (const float*)d_in[4];
  const float* bq    = (const float*)d_in[5];
  const float* Wk    = (const float*)d_in[6];
  const float* bk    = (const float*)d_in[7];
  const float* Wv    = (const float*)d_in[8];
  const float* bv    = (const float*)d_in[9];
  const float* Wo    = (const float*)d_in[10];
  const float* bo    = (const float*)d_in[11];
  const float* ln1g  = (const float*)d_in[12];
  const float* ln1b  = (const float*)d_in[13];
  const float* ln2g  = (const float*)d_in[14];
  const float* ln2b  = (const float*)d_in[15];
  const float* W1    = (const float*)d_in[16];
  const float* b1    = (const float*)d_in[17];
  const float* W2    = (const float*)d_in[18];
  const float* b2    = (const float*)d_in[19];
  const float* flng  = (const float*)d_in[20];
  const float* flnb  = (const float*)d_in[21];
  const float* clsW  = (const float*)d_in[22];
  const float* clsb  = (const float*)d_in[23];

  float* x = (float*)d_ws;
  bf16* h  = (bf16*)(x + (size_t)BSn * Hn);
  bf16* cb = h + (size_t)BSn * Hn;
  bf16* qb = cb;                          // [BSn][Hn]
  bf16* kb = cb + (size_t)BSn * Hn;       // [BSn][Hn]
  bf16* vtb = cb + 2 * (size_t)BSn * Hn;  // V^T [Bn][Hn][Sn]
  bf16* scb = cb + 3 * (size_t)BSn * Hn;  // [Bn, CQ, Sn]
  bf16* wt = cb + (size_t)BSn * FFn;
  bf16* wqT = wt;                                   // wq,wk,wv contiguous
  bf16* woT = wqT + 3 * (size_t)Hn * Hn;
  bf16* w1T = woT + (size_t)Hn * Hn;                // [FF][H]
  bf16* w2T = w1T + (size_t)Hn * FFn;               // [H][FF]

  const int M = BSn;
  dim3 blk(256);
  dim3 gridQK(Sn / 128, CQ / 128, Bn);
  dim3 gridSM(CQ, Bn);
  dim3 gridPV(Hn / 128, CQ / 128, Bn);

  embed_kernel<<<BSn, blk, 0, stream>>>(ids, tok, pos, x);

  for (int l = 0; l < Ln; l++) {
    const float* Wq_l = Wq + (size_t)l * Hn * Hn;
    const float* Wk_l = Wk + (size_t)l * Hn * Hn;
    const float* Wv_l = Wv + (size_t)l * Hn * Hn;
    const float* Wo_l = Wo + (size_t)l * Hn * Hn;
    const float* W1_l = W1 + (size_t)l * Hn * FFn;
    const float* W2_l = W2 + (size_t)l * FFn * Hn;

    transpose_all_kernel<<<6912, blk, 0, stream>>>(Wq_l, Wk_l, Wv_l, Wo_l,
                                                   W1_l, W2_l, wt);

    // --- attention block ---
    ln_kernel<<<BSn, blk, 0, stream>>>(x, ln1g + l * Hn, ln1b + l * Hn, h);
    // fused QKV (M=16384, N=2304, K=768): 18*128 = 2304 blocks
    gemm128_kernel<4, bf16><<<2304, blk, 0, stream>>>(
        h, wqT, bq + l * Hn, nullptr, qb, M, 3 * Hn, Hn,
        bk + l * Hn, bv + l * Hn);
    for (int c = 0; c < Sn / CQ; c++) {
      int q0 = c * CQ;
      qk_mfma_kernel<<<gridQK, blk, 0, stream>>>(qb, kb, scb, q0);
      softmax_kernel<<<gridSM, blk, 0, stream>>>(scb, mask, q0);
      pv_mfma_kernel<<<gridPV, blk, 0, stream>>>(scb, vtb, h, q0);
    }
    // Wo (N=768, K=768): 6*128 = 768 blocks
    gemm128_kernel<1, float><<<768, blk, 0, stream>>>(
        h, woT, bo + l * Hn, x, x, M, Hn, Hn, nullptr, nullptr);

    // --- FFN block ---
    ln_kernel<<<BSn, blk, 0, stream>>>(x, ln2g + l * Hn, ln2b + l * Hn, h);
    // W1 (N=3072, K=768): 24*128 = 3072 blocks
    gemm128_kernel<2, bf16><<<3072, blk, 0, stream>>>(
        h, w1T, b1 + l * FFn, nullptr, cb, M, FFn, Hn, nullptr, nullptr);
    // W2 (N=768, K=3072): 768 blocks
    gemm128_kernel<1, float><<<768, blk, 0, stream>>>(
        cb, w2T, b2 + l * Hn, x, x, M, Hn, FFn, nullptr, nullptr);
  }

  ln_kernel<<<BSn, blk, 0, stream>>>(x, flng, flnb, h);
  cls_kernel<<<Bn, blk, 0, stream>>>(h, mask, clsW, clsb, (float*)d_out);
}